// Round 9
// baseline (151.571 us; speedup 1.0000x reference)
//
#include <hip/hip_runtime.h>

#define NQ 9
#define NS 512            // 2^9 amplitudes
#define M2 1024           // [Re V; Im V] stacked rows

#define COEF_ROT_BASE (72*32)                 // 72 ent steps x 32 floats
#define COEF_FLOATS   (COEF_ROT_BASE + 27*8)  // + 27 rots x 8 floats = 2520

typedef __attribute__((ext_vector_type(8))) short bf16x8;
typedef __attribute__((ext_vector_type(4))) float f32x4;

__device__ inline unsigned short f2bf(float f){
  unsigned int u = __float_as_uint(f);
  u += 0x7fffu + ((u >> 16) & 1u);   // round-to-nearest-even
  return (unsigned short)(u >> 16);
}

// =====================  coefficient precompute (tiny kernel, global out)  =====================
// Slot g = blk*9 + I (32 floats):
//   I in {0,1,2,8}  : pre-permuted H table  Hx[p][d]=Gx[p][p^d] (16) + Hy (16)
//   I in {3..7}     : {c0,s0,c1,s1,Ax,Ay,Bx,By} uniform 3-round coefs
// Rot r = layer*9+wire at COEF_ROT_BASE + r*8: side0 {u00x,u00y,u01x,u01y}, side1 {u11x,u11y,u10x,u10y}
__global__ __launch_bounds__(128) void precoef(const float* __restrict__ params,
                                               const float* __restrict__ weights,
                                               const float* __restrict__ params2,
                                               float* __restrict__ coef){
  int tid = threadIdx.x;
  if (tid < 72){
    int blk = tid / 9, I = tid % 9;
    const float* p = (blk < 3) ? params + blk*36 : params2 + (blk-3)*36;
    float s0,c0,s1,c1,s2,c2,s3,c3;
    __sincosf(0.5f*p[4*I+0], &s0, &c0);
    __sincosf(0.5f*p[4*I+1], &s1, &c1);
    __sincosf(0.5f*p[4*I+2], &s2, &c2);
    __sincosf(0.5f*p[4*I+3], &s3, &c3);
    float* dst = coef + tid*32;
    if (I == 0 || I == 1 || I == 2 || I == 8){
      float m[4][4] = {
        { c0*c1, -c0*s1, -s0*c1,  s0*s1},
        { c0*s1,  c0*c1, -s0*s1, -s0*c1},
        { s0*c1, -s0*s1,  c0*c1, -c0*s1},
        { s0*s1,  s0*c1,  c0*s1,  c0*c1}};
      float gx[4][4], gy[4][4];
      #pragma unroll
      for (int q = 0; q < 4; ++q){
        gx[0][q] = m[1][q];  gy[0][q] = 0.f;      // row swap from X(q_target)
        gx[1][q] = m[0][q];  gy[1][q] = 0.f;
        gx[2][q] =  c3*c2*m[2][q] - s3*s2*m[3][q];
        gy[2][q] =  c3*s2*m[2][q] - s3*c2*m[3][q];
        gx[3][q] =  s3*s2*m[2][q] + c3*c2*m[3][q];
        gy[3][q] = -(s3*c2*m[2][q] + c3*s2*m[3][q]);
      }
      #pragma unroll
      for (int pp = 0; pp < 4; ++pp)
        #pragma unroll
        for (int d = 0; d < 4; ++d){
          dst[pp*4+d]    = gx[pp][pp^d];
          dst[16+pp*4+d] = gy[pp][pp^d];
        }
    } else {
      dst[0] = c0;  dst[1] = s0;
      dst[2] = c1;  dst[3] = s1;
      dst[4] =  c3*c2;  dst[5] =  c3*s2;   // A
      dst[6] = -s3*s2;  dst[7] = -s3*c2;   // B
      #pragma unroll
      for (int k = 8; k < 32; ++k) dst[k] = 0.f;
    }
  } else if (tid < 99){
    int r = tid - 72;
    int l = r / 9, i = r % 9;
    const float* w = weights + l*27 + 3*i;
    float phi = w[0], th = w[1], om = w[2];
    float sT,cT,sA,cA,sB,cB;
    __sincosf(0.5f*th, &sT, &cT);
    __sincosf(0.5f*(phi+om), &sA, &cA);
    __sincosf(0.5f*(om-phi), &sB, &cB);
    float* dst = coef + COEF_ROT_BASE + r*8;
    dst[0] =  cA*cT;  dst[1] = -sA*cT;   // side 0: u00 (diag), u01 (off)
    dst[2] = -cB*sT;  dst[3] =  sB*sT;
    dst[4] =  cA*cT;  dst[5] =  sA*cT;   // side 1: u11 (diag), u10 (off)
    dst[6] =  cB*sT;  dst[7] =  sB*sT;
  }
}

// =====================  8-wave, 1-amp-per-lane statevector sim  =====================
// Thread tid holds amp i = tid: bits 0-5 lane, bits 6-8 wave. Wire w <-> bit (8-w).

template<int LM>
__device__ inline float lxor(float v){
  if constexpr (LM == 1)
    return __int_as_float(__builtin_amdgcn_mov_dpp(__float_as_int(v), 0xB1, 0xF, 0xF, true));
  else if constexpr (LM == 2)
    return __int_as_float(__builtin_amdgcn_mov_dpp(__float_as_int(v), 0x4E, 0xF, 0xF, true));
  else if constexpr (LM == 3)
    return __int_as_float(__builtin_amdgcn_mov_dpp(__float_as_int(v), 0x1B, 0xF, 0xF, true));
  else if constexpr (LM < 32)
    return __int_as_float(__builtin_amdgcn_ds_swizzle(__float_as_int(v), (LM<<10)|0x1F));
  else
    return __shfl_xor(v, LM);
}

// fused 4x4 step via LDS image; at least one of CM/TM is a wave bit.
// H rows read from global (uniform addresses) and value-selected.
template<int CM, int TM>
__device__ inline void step_h(float& ax, float& ay, int i, float2* sh,
                              const float* __restrict__ g){
  __syncthreads();
  sh[i] = make_float2(ax, ay);
  __syncthreads();
  float2 tv = sh[i ^ TM];
  float2 cv = sh[i ^ CM];
  float2 bv = sh[i ^ (CM ^ TM)];
  bool cb = (i & CM) != 0, tb = (i & TM) != 0;
  float hx[4], hy[4];
  #pragma unroll
  for (int d = 0; d < 4; ++d){
    hx[d] = cb ? (tb ? g[12+d] : g[8+d]) : (tb ? g[4+d] : g[d]);
    hy[d] = cb ? (tb ? g[28+d] : g[24+d]) : (tb ? g[20+d] : g[16+d]);
  }
  float ox = ax, oy = ay;
  ax = hx[0]*ox - hy[0]*oy + hx[1]*tv.x - hy[1]*tv.y
     + hx[2]*cv.x - hy[2]*cv.y + hx[3]*bv.x - hy[3]*bv.y;
  ay = hx[0]*oy + hy[0]*ox + hx[1]*tv.y + hy[1]*tv.x
     + hx[2]*cv.y + hy[2]*cv.x + hx[3]*bv.y + hy[3]*bv.x;
}

// 3-round ent step, both wires in lane bits; all coefs wave-uniform (scalar loads).
template<int CM, int TM>
__device__ inline void step_3r(float& ax, float& ay, int lane,
                               const float* __restrict__ g){
  float c0=g[0], s0=g[1], c1=g[2], s1=g[3];
  float Ax=g[4], Ay=g[5], Bx=g[6], By=g[7];
  {  // RY(th0) on ctrl bit
    float px = lxor<CM>(ax), py = lxor<CM>(ay);
    float se = (lane & CM) ? s0 : -s0;
    ax = c0*ax + se*px;  ay = c0*ay + se*py;
  }
  {  // RY(th1) on target bit
    float px = lxor<TM>(ax), py = lxor<TM>(ay);
    float se = (lane & TM) ? s1 : -s1;
    ax = c1*ax + se*px;  ay = c1*ay + se*py;
  }
  {  // fused CNOT*CRZ*X*CRX
    float px = lxor<TM>(ax), py = lxor<TM>(ay);
    bool tb = (lane & TM) != 0;
    float Ay2 = tb ? -Ay : Ay, Bx2 = tb ? -Bx : Bx;
    float nx = Ax*ax - Ay2*ay + Bx2*px - By*py;
    float ny = Ax*ay + Ay2*ax + Bx2*py + By*px;
    bool cb = (lane & CM) != 0;
    ax = cb ? nx : px;  ay = cb ? ny : py;
  }
}

// Rot on a wave-bit wire via LDS image
template<int PM>
__device__ inline void rot_img(float& ax, float& ay, int i, float2* sh,
                               const float* __restrict__ u){
  __syncthreads();
  sh[i] = make_float2(ax, ay);
  __syncthreads();
  float2 pv = sh[i ^ PM];
  bool hi = (i & PM) != 0;
  float u0 = hi?u[4]:u[0], u1 = hi?u[5]:u[1], u2 = hi?u[6]:u[2], u3 = hi?u[7]:u[3];
  float nx = u0*ax - u1*ay + u2*pv.x - u3*pv.y;
  float ny = u0*ay + u1*ax + u2*pv.y + u3*pv.x;
  ax = nx; ay = ny;
}

// Rot on a lane-bit wire
template<int LM>
__device__ inline void rot_swz(float& ax, float& ay, int lane,
                               const float* __restrict__ u){
  float px = lxor<LM>(ax), py = lxor<LM>(ay);
  bool hi = (lane & LM) != 0;
  float u0 = hi?u[4]:u[0], u1 = hi?u[5]:u[1], u2 = hi?u[6]:u[2], u3 = hi?u[7]:u[3];
  float nx = u0*ax - u1*ay + u2*px - u3*py;
  float ny = u0*ay + u1*ax + u2*py + u3*px;
  ax = nx; ay = ny;
}

// CNOT ring of range R (runtime): one LDS permutation round-trip.
__device__ inline void ring_rt(float& ax, float& ay, int i, float2* sh, int R){
  __syncthreads();
  sh[i] = make_float2(ax, ay);
  __syncthreads();
  int s = i;
  for (int k = 8; k >= 0; --k){
    int bc = 8 - k;
    int it = k + R; if (it >= 9) it -= 9;
    int bt = 8 - it;
    s ^= ((s >> bc) & 1) << bt;
  }
  float2 v = sh[s];
  ax = v.x; ay = v.y;
}

// ---------------- loopable drivers ----------------

template<int I = 0>
__device__ inline void ent_blk(float& ax, float& ay, int i, int lane, float2* sh,
                               const float* __restrict__ S){
  const float* g = S + I*32;
  if constexpr      (I == 0) step_h<0x100,0x080>(ax, ay, i, sh, g);
  else if constexpr (I == 1) step_h<0x080,0x040>(ax, ay, i, sh, g);
  else if constexpr (I == 2) step_h<0x040,0x020>(ax, ay, i, sh, g);
  else if constexpr (I == 8) step_h<0x001,0x100>(ax, ay, i, sh, g);
  else                       step_3r<(1<<(8-I)),(1<<(7-I))>(ax, ay, lane, g);
  if constexpr (I < 8) ent_blk<I+1>(ax, ay, i, lane, sh, S);
}

template<int I = 0>
__device__ inline void sel_rots(float& ax, float& ay, int i, int lane, float2* sh,
                                const float* __restrict__ ub){
  const float* u = ub + I*8;
  if constexpr      (I == 0) rot_img<0x100>(ax, ay, i, sh, u);
  else if constexpr (I == 1) rot_img<0x080>(ax, ay, i, sh, u);
  else if constexpr (I == 2) rot_img<0x040>(ax, ay, i, sh, u);
  else                       rot_swz<(1<<(8-I))>(ax, ay, lane, u);
  if constexpr (I < 8) sel_rots<I+1>(ax, ay, i, lane, sh, ub);
}

// Combined kernel: blocks [0,NS) simulate one V column each; blocks >= NS run prep.
__global__ __launch_bounds__(512) void sim_prep(const float* __restrict__ coef,
                                                const float* __restrict__ adds,
                                                unsigned short* __restrict__ A2,
                                                unsigned short* __restrict__ cT,
                                                float* __restrict__ out, int B){
  __shared__ float2 sh[512];
  int tid = threadIdx.x;

  if (blockIdx.x >= NS){
    // ---- prep path: build c (wave per sample) + zero the output accumulator ----
    int gid = (blockIdx.x - NS) * 512 + tid;
    int b = gid >> 6;
    int lane = gid & 63;
    if (b < B){
      const float* ab = adds + b * NQ;
      float cw[NQ], sw[NQ];
      #pragma unroll
      for (int w = 0; w < NQ; ++w)
        __sincosf(0.5f * ab[w], &sw[w], &cw[w]);
      float p6 = 1.f;
      #pragma unroll
      for (int w = 0; w < 6; ++w)
        p6 *= ((lane >> (5 - w)) & 1) ? sw[w] : cw[w];
      union { unsigned short u[8]; uint4 v; } pk;
      #pragma unroll
      for (int j = 0; j < 8; ++j){
        float p = p6 * (((j>>2)&1) ? sw[6] : cw[6])
                     * (((j>>1)&1) ? sw[7] : cw[7])
                     * (( j    &1) ? sw[8] : cw[8]);
        pk.u[j] = f2bf(p);
      }
      *(uint4*)(cT + (size_t)b * NS + lane*8) = pk.v;
    }
    if (gid < B) out[gid] = 0.f;
    return;
  }

  // ---- sim path ----
  int t = blockIdx.x;
  int i = tid;
  int lane = tid & 63;
  float ax, ay;
  int pc = __popc((unsigned)t) & 3;
  float prx = (pc==0) ? 1.f : (pc==2 ? -1.f : 0.f);
  float pry = (pc==3) ? 1.f : (pc==1 ? -1.f : 0.f);
  ax = (i == t) ? prx : 0.f;
  ay = (i == t) ? pry : 0.f;

  #pragma unroll 1
  for (int blk = 0; blk < 3; ++blk)
    ent_blk<0>(ax, ay, i, lane, sh, coef + blk*288);
  #pragma unroll 1
  for (int L = 0; L < 3; ++L){
    sel_rots<0>(ax, ay, i, lane, sh, coef + COEF_ROT_BASE + L*72);
    ring_rt(ax, ay, i, sh, L + 1);
  }
  #pragma unroll 1
  for (int blk = 3; blk < 8; ++blk)
    ent_blk<0>(ax, ay, i, lane, sh, coef + blk*288);

  A2[(size_t)i * NS + t]        = f2bf(ax);
  A2[(size_t)(i + NS) * NS + t] = f2bf(ay);
}

// Phi2 = A2(1024x512) @ c(512xB); out[b] = sum_row sign(row) * Phi2[row][b]^2,
// sign(row) = -1 iff (row & 256).
__global__ __launch_bounds__(256) void gemm_out(const unsigned short* __restrict__ A2,
                                                const unsigned short* __restrict__ cT,
                                                float* __restrict__ out){
  int bx = blockIdx.x;            // N tile (128 cols of b)
  int by = blockIdx.y;            // M tile (128 rows), 8 tiles
  int tid = threadIdx.x;
  int wave = tid >> 6, lane = tid & 63;
  int wy = wave >> 1, wx = wave & 1;
  int lane15 = lane & 15, quad = lane >> 4;
  int rowBase = by*128 + wy*64;
  int colBase = bx*128 + wx*64;
  const short* Ap = (const short*)A2;   // [row][k]
  const short* Bp = (const short*)cT;   // [col][k]

  f32x4 acc[4][4];
  #pragma unroll
  for (int i = 0; i < 4; ++i)
    #pragma unroll
    for (int j = 0; j < 4; ++j)
      acc[i][j] = (f32x4){0.f, 0.f, 0.f, 0.f};

  #pragma unroll 2
  for (int k0 = 0; k0 < NS; k0 += 32){
    bf16x8 a[4], b[4];
    #pragma unroll
    for (int mi = 0; mi < 4; ++mi)
      a[mi] = *(const bf16x8*)(Ap + (size_t)(rowBase + mi*16 + lane15)*NS + k0 + quad*8);
    #pragma unroll
    for (int ni = 0; ni < 4; ++ni)
      b[ni] = *(const bf16x8*)(Bp + (size_t)(colBase + ni*16 + lane15)*NS + k0 + quad*8);
    #pragma unroll
    for (int mi = 0; mi < 4; ++mi)
      #pragma unroll
      for (int ni = 0; ni < 4; ++ni)
        acc[mi][ni] = __builtin_amdgcn_mfma_f32_16x16x32_bf16(a[mi], b[ni], acc[mi][ni], 0, 0, 0);
  }

  float sign = (by & 2) ? -1.f : 1.f;
  #pragma unroll
  for (int ni = 0; ni < 4; ++ni){
    float cs = 0.f;
    #pragma unroll
    for (int mi = 0; mi < 4; ++mi)
      #pragma unroll
      for (int r = 0; r < 4; ++r)
        cs += acc[mi][ni][r] * acc[mi][ni][r];
    cs += __shfl_xor(cs, 16);
    cs += __shfl_xor(cs, 32);
    if (quad == 0)
      atomicAdd(out + colBase + ni*16 + lane15, sign * cs);
  }
}

extern "C" void kernel_launch(void* const* d_in, const int* in_sizes, int n_in,
                              void* d_out, int out_size, void* d_ws, size_t ws_size,
                              hipStream_t stream) {
  const float* adds    = (const float*)d_in[0];
  const float* params  = (const float*)d_in[1];
  const float* weights = (const float*)d_in[2];
  const float* params2 = (const float*)d_in[3];
  float* out = (float*)d_out;
  int B = in_sizes[0] / NQ;   // 8192

  unsigned short* A2 = (unsigned short*)d_ws;        // 1024*512 bf16 = 1 MB
  unsigned short* cT = A2 + (size_t)M2 * NS;         // B*512 bf16 = 8 MB
  float* coef = (float*)(cT + (size_t)B * NS);       // 2520 floats

  int prepBlocks = (B * 64 + 511) / 512;             // 1024
  hipLaunchKernelGGL(precoef, dim3(1), dim3(128), 0, stream, params, weights, params2, coef);
  hipLaunchKernelGGL(sim_prep, dim3(NS + prepBlocks), dim3(512), 0, stream,
                     coef, adds, A2, cT, out, B);
  hipLaunchKernelGGL(gemm_out, dim3(B / 128, 8), dim3(256), 0, stream, A2, cT, out);
}

// Round 10
// 118.285 us; speedup vs baseline: 1.2814x; 1.2814x over previous
//
#include <hip/hip_runtime.h>

#define NQ 9
#define NS 512            // 2^9 amplitudes
#define M2 1024           // [Re V; Im V] stacked rows

#define COEF_ROT_BASE (72*32)                 // 72 ent steps x 32 floats
#define COEF_R3_BASE  (COEF_ROT_BASE + 27*8)  // + 27 rots x 8 floats
#define COEF_FLOATS   (COEF_R3_BASE + 3*128)  // + 3 merged 8x8 rot tables = 3288

typedef __attribute__((ext_vector_type(8))) short bf16x8;
typedef __attribute__((ext_vector_type(4))) float f32x4;

__device__ inline unsigned short f2bf(float f){
  unsigned int u = __float_as_uint(f);
  u += 0x7fffu + ((u >> 16) & 1u);   // round-to-nearest-even
  return (unsigned short)(u >> 16);
}

// =====================  8-wave, 1-amp-per-lane statevector sim  =====================
// Thread tid holds amp i = tid: bits 0-5 lane, bits 6-8 wave. Wire w <-> bit (8-w).
// LDS state images ping-pong: each exchange round = write buf -> 1 barrier -> read buf.

template<int LM>
__device__ inline float lxor(float v){
  if constexpr (LM == 1)
    return __int_as_float(__builtin_amdgcn_mov_dpp(__float_as_int(v), 0xB1, 0xF, 0xF, true));
  else if constexpr (LM == 2)
    return __int_as_float(__builtin_amdgcn_mov_dpp(__float_as_int(v), 0x4E, 0xF, 0xF, true));
  else if constexpr (LM == 3)
    return __int_as_float(__builtin_amdgcn_mov_dpp(__float_as_int(v), 0x1B, 0xF, 0xF, true));
  else if constexpr (LM < 32)
    return __int_as_float(__builtin_amdgcn_ds_swizzle(__float_as_int(v), (LM<<10)|0x1F));
  else
    return __shfl_xor(v, LM);
}

// fused 4x4 step via LDS image (ping-pong buf); coefs from LDS, lane-indexed b128.
template<int CM, int TM>
__device__ inline void step_h(float& ax, float& ay, int i, float2* buf,
                              const float* g){
  buf[i] = make_float2(ax, ay);
  __syncthreads();
  float2 tv = buf[i ^ TM];
  float2 cv = buf[i ^ CM];
  float2 bv = buf[i ^ (CM ^ TM)];
  int p = ((i & CM) ? 2 : 0) | ((i & TM) ? 1 : 0);
  float4 hx = *(const float4*)(g + p*4);
  float4 hy = *(const float4*)(g + 16 + p*4);
  float ox = ax, oy = ay;
  ax = hx.x*ox - hy.x*oy + hx.y*tv.x - hy.y*tv.y
     + hx.z*cv.x - hy.z*cv.y + hx.w*bv.x - hy.w*bv.y;
  ay = hx.x*oy + hy.x*ox + hx.y*tv.y + hy.y*tv.x
     + hx.z*cv.y + hy.z*cv.x + hx.w*bv.y + hy.w*bv.x;
}

// fused 4x4 step, both wires in lane bits -> pure cross-lane, no barrier
template<int CM, int TM>
__device__ inline void step_swz(float& ax, float& ay, int lane, const float* g){
  float tx = lxor<TM>(ax),      ty = lxor<TM>(ay);
  float cx = lxor<CM>(ax),      cy = lxor<CM>(ay);
  float bx = lxor<(CM^TM)>(ax), by = lxor<(CM^TM)>(ay);
  int p = ((lane & CM) ? 2 : 0) | ((lane & TM) ? 1 : 0);
  float4 hx = *(const float4*)(g + p*4);
  float4 hy = *(const float4*)(g + 16 + p*4);
  float ox = ax, oy = ay;
  ax = hx.x*ox - hy.x*oy + hx.y*tx - hy.y*ty
     + hx.z*cx - hy.z*cy + hx.w*bx - hy.w*by;
  ay = hx.x*oy + hy.x*ox + hx.y*ty + hy.y*tx
     + hx.z*cy + hy.z*cx + hx.w*by + hy.w*bx;
}

// merged Rot(w0)xRot(w1)xRot(w2) on the 3 wave bits: one 8-partner LDS round.
// M = row p (8 complex, wave-uniform, p = i>>6).
__device__ inline void rot3_img(float& ax, float& ay, int i, float2* buf,
                                const float* M){
  buf[i] = make_float2(ax, ay);
  __syncthreads();
  int base = i & 63;
  float nx = 0.f, ny = 0.f;
  #pragma unroll
  for (int q = 0; q < 8; ++q){
    float2 v = buf[(q << 6) | base];
    float mx = M[q*2], my = M[q*2+1];
    nx += mx*v.x - my*v.y;
    ny += mx*v.y + my*v.x;
  }
  ax = nx; ay = ny;
}

// Rot on a lane-bit wire; coef side-selected b128 from LDS
template<int LM>
__device__ inline void rot_swz(float& ax, float& ay, int lane, const float* u){
  float px = lxor<LM>(ax), py = lxor<LM>(ay);
  float4 uu = *(const float4*)(u + ((lane & LM) ? 4 : 0));
  float nx = uu.x*ax - uu.y*ay + uu.z*px - uu.w*py;
  float ny = uu.x*ay + uu.y*ax + uu.z*py + uu.w*px;
  ax = nx; ay = ny;
}

// CNOT ring of range R (runtime): one LDS permutation round (ping-pong buf).
__device__ inline void ring_rt(float& ax, float& ay, int i, float2* buf, int R){
  buf[i] = make_float2(ax, ay);
  __syncthreads();
  int s = i;
  for (int k = 8; k >= 0; --k){
    int bc = 8 - k;
    int it = k + R; if (it >= 9) it -= 9;
    int bt = 8 - it;
    s ^= ((s >> bc) & 1) << bt;
  }
  float2 v = buf[s];
  ax = v.x; ay = v.y;
}

// ---------------- loopable drivers ----------------
// Buffer schedule (strict alternation across all LDS rounds):
//   ent block: I0->A, I1->B, I2->A, I8->B   (4 rounds)
//   SEL layer: rot3->A, ring->B             (2 rounds)

template<int I = 0>
__device__ inline void ent_blk(float& ax, float& ay, int i, int lane,
                               float2* bufA, float2* bufB, const float* S){
  const float* g = S + I*32;
  if constexpr      (I == 0) step_h<0x100,0x080>(ax, ay, i, bufA, g);
  else if constexpr (I == 1) step_h<0x080,0x040>(ax, ay, i, bufB, g);
  else if constexpr (I == 2) step_h<0x040,0x020>(ax, ay, i, bufA, g);
  else if constexpr (I == 8) step_h<0x001,0x100>(ax, ay, i, bufB, g);
  else                       step_swz<(1<<(8-I)),(1<<(7-I))>(ax, ay, lane, g);
  if constexpr (I < 8) ent_blk<I+1>(ax, ay, i, lane, bufA, bufB, S);
}

template<int I = 3>
__device__ inline void sel_lane_rots(float& ax, float& ay, int lane,
                                     const float* ub){
  rot_swz<(1<<(8-I))>(ax, ay, lane, ub + I*8);
  if constexpr (I < 8) sel_lane_rots<I+1>(ax, ay, lane, ub);
}

// Combined kernel: blocks [0,NS) simulate one V column each; blocks >= NS run prep.
__global__ __launch_bounds__(512) void sim_prep(const float* __restrict__ params,
                                                const float* __restrict__ weights,
                                                const float* __restrict__ params2,
                                                const float* __restrict__ adds,
                                                unsigned short* __restrict__ A2,
                                                unsigned short* __restrict__ cT,
                                                float* __restrict__ out, int B){
  int tid = threadIdx.x;

  if (blockIdx.x >= NS){
    // ---- prep path: build c (wave per sample) + zero the output accumulator ----
    int gid = (blockIdx.x - NS) * 512 + tid;
    int b = gid >> 6;
    int lane = gid & 63;
    if (b < B){
      const float* ab = adds + b * NQ;
      float cw[NQ], sw[NQ];
      #pragma unroll
      for (int w = 0; w < NQ; ++w)
        __sincosf(0.5f * ab[w], &sw[w], &cw[w]);
      float p6 = 1.f;
      #pragma unroll
      for (int w = 0; w < 6; ++w)
        p6 *= ((lane >> (5 - w)) & 1) ? sw[w] : cw[w];
      union { unsigned short u[8]; uint4 v; } pk;
      #pragma unroll
      for (int j = 0; j < 8; ++j){
        float p = p6 * (((j>>2)&1) ? sw[6] : cw[6])
                     * (((j>>1)&1) ? sw[7] : cw[7])
                     * (( j    &1) ? sw[8] : cw[8]);
        pk.u[j] = f2bf(p);
      }
      *(uint4*)(cT + (size_t)b * NS + lane*8) = pk.v;
    }
    if (gid < B) out[gid] = 0.f;
    return;
  }

  // ---- sim path ----
  __shared__ float2 bufA[512];
  __shared__ float2 bufB[512];
  __shared__ float scoef[COEF_FLOATS];

  // inline coefficient precompute into LDS
  if (tid < 72){
    int blk = tid / 9, I = tid % 9;
    const float* p = (blk < 3) ? params + blk*36 : params2 + (blk-3)*36;
    float s0,c0,s1,c1,s2,c2,s3,c3;
    __sincosf(0.5f*p[4*I+0], &s0, &c0);
    __sincosf(0.5f*p[4*I+1], &s1, &c1);
    __sincosf(0.5f*p[4*I+2], &s2, &c2);
    __sincosf(0.5f*p[4*I+3], &s3, &c3);
    float m[4][4] = {
      { c0*c1, -c0*s1, -s0*c1,  s0*s1},
      { c0*s1,  c0*c1, -s0*s1, -s0*c1},
      { s0*c1, -s0*s1,  c0*c1, -c0*s1},
      { s0*s1,  s0*c1,  c0*s1,  c0*c1}};
    float gx[4][4], gy[4][4];
    #pragma unroll
    for (int q = 0; q < 4; ++q){
      gx[0][q] = m[1][q];  gy[0][q] = 0.f;      // row swap from X(q_target)
      gx[1][q] = m[0][q];  gy[1][q] = 0.f;
      gx[2][q] =  c3*c2*m[2][q] - s3*s2*m[3][q];
      gy[2][q] =  c3*s2*m[2][q] - s3*c2*m[3][q];
      gx[3][q] =  s3*s2*m[2][q] + c3*c2*m[3][q];
      gy[3][q] = -(s3*c2*m[2][q] + c3*s2*m[3][q]);
    }
    float* dst = scoef + tid*32;
    #pragma unroll
    for (int pp = 0; pp < 4; ++pp)
      #pragma unroll
      for (int d = 0; d < 4; ++d){
        dst[pp*4+d]    = gx[pp][pp^d];   // Hx[p][d] = Gx[p][p^d]
        dst[16+pp*4+d] = gy[pp][pp^d];
      }
  } else if (tid < 99){
    int r = tid - 72;
    int l = r / 9, i = r % 9;
    const float* w = weights + l*27 + 3*i;
    float phi = w[0], th = w[1], om = w[2];
    float sT,cT,sA,cA,sB,cB;
    __sincosf(0.5f*th, &sT, &cT);
    __sincosf(0.5f*(phi+om), &sA, &cA);
    __sincosf(0.5f*(om-phi), &sB, &cB);
    float* dst = scoef + COEF_ROT_BASE + r*8;
    dst[0] =  cA*cT;  dst[1] = -sA*cT;   // side 0: u00 (diag), u01 (off)
    dst[2] = -cB*sT;  dst[3] =  sB*sT;
    dst[4] =  cA*cT;  dst[5] =  sA*cT;   // side 1: u11 (diag), u10 (off)
    dst[6] =  cB*sT;  dst[7] =  sB*sT;
  } else if (tid < 123){
    // merged Rot(w0) x Rot(w1) x Rot(w2) tables: 24 threads = (layer l, row p)
    int idx = tid - 99;
    int l = idx >> 3, p = idx & 7;
    float e0x[3], e0y[3], e1x[3], e1y[3];   // row p_w of U_w: entries q_w=0,1
    #pragma unroll
    for (int w = 0; w < 3; ++w){
      const float* wp = weights + l*27 + 3*w;
      float phi = wp[0], th = wp[1], om = wp[2];
      float sT,cT,sA,cA,sB,cB;
      __sincosf(0.5f*th, &sT, &cT);
      __sincosf(0.5f*(phi+om), &sA, &cA);
      __sincosf(0.5f*(om-phi), &sB, &cB);
      int pw = (p >> (2 - w)) & 1;
      if (pw == 0){ e0x[w] =  cA*cT; e0y[w] = -sA*cT; e1x[w] = -cB*sT; e1y[w] =  sB*sT; }
      else        { e0x[w] =  cB*sT; e0y[w] =  sB*sT; e1x[w] =  cA*cT; e1y[w] =  sA*cT; }
    }
    float* dst = scoef + COEF_R3_BASE + l*128 + p*16;
    #pragma unroll
    for (int q = 0; q < 8; ++q){
      float rx = 1.f, ry = 0.f;
      #pragma unroll
      for (int w = 0; w < 3; ++w){
        int qw = (q >> (2 - w)) & 1;
        float fx = qw ? e1x[w] : e0x[w];
        float fy = qw ? e1y[w] : e0y[w];
        float nx = rx*fx - ry*fy;
        float ny = rx*fy + ry*fx;
        rx = nx; ry = ny;
      }
      dst[q*2]   = rx;
      dst[q*2+1] = ry;
    }
  }
  __syncthreads();

  int t = blockIdx.x;
  int i = tid;
  int lane = tid & 63;
  float ax, ay;
  int pc = __popc((unsigned)t) & 3;
  float prx = (pc==0) ? 1.f : (pc==2 ? -1.f : 0.f);
  float pry = (pc==3) ? 1.f : (pc==1 ? -1.f : 0.f);
  ax = (i == t) ? prx : 0.f;
  ay = (i == t) ? pry : 0.f;

  #pragma unroll 1
  for (int blk = 0; blk < 3; ++blk)
    ent_blk<0>(ax, ay, i, lane, bufA, bufB, scoef + blk*288);
  #pragma unroll 1
  for (int L = 0; L < 3; ++L){
    rot3_img(ax, ay, i, bufA, scoef + COEF_R3_BASE + L*128 + (i>>6)*16);
    sel_lane_rots<3>(ax, ay, lane, scoef + COEF_ROT_BASE + L*72);
    ring_rt(ax, ay, i, bufB, L + 1);
  }
  #pragma unroll 1
  for (int blk = 3; blk < 8; ++blk)
    ent_blk<0>(ax, ay, i, lane, bufA, bufB, scoef + blk*288);

  A2[(size_t)i * NS + t]        = f2bf(ax);
  A2[(size_t)(i + NS) * NS + t] = f2bf(ay);
}

// Phi2 = A2(1024x512) @ c(512xB); out[b] = sum_row sign(row) * Phi2[row][b]^2,
// sign(row) = -1 iff (row & 256).
__global__ __launch_bounds__(256) void gemm_out(const unsigned short* __restrict__ A2,
                                                const unsigned short* __restrict__ cT,
                                                float* __restrict__ out){
  int bx = blockIdx.x;            // N tile (128 cols of b)
  int by = blockIdx.y;            // M tile (128 rows), 8 tiles
  int tid = threadIdx.x;
  int wave = tid >> 6, lane = tid & 63;
  int wy = wave >> 1, wx = wave & 1;
  int lane15 = lane & 15, quad = lane >> 4;
  int rowBase = by*128 + wy*64;
  int colBase = bx*128 + wx*64;
  const short* Ap = (const short*)A2;   // [row][k]
  const short* Bp = (const short*)cT;   // [col][k]

  f32x4 acc[4][4];
  #pragma unroll
  for (int i = 0; i < 4; ++i)
    #pragma unroll
    for (int j = 0; j < 4; ++j)
      acc[i][j] = (f32x4){0.f, 0.f, 0.f, 0.f};

  #pragma unroll 2
  for (int k0 = 0; k0 < NS; k0 += 32){
    bf16x8 a[4], b[4];
    #pragma unroll
    for (int mi = 0; mi < 4; ++mi)
      a[mi] = *(const bf16x8*)(Ap + (size_t)(rowBase + mi*16 + lane15)*NS + k0 + quad*8);
    #pragma unroll
    for (int ni = 0; ni < 4; ++ni)
      b[ni] = *(const bf16x8*)(Bp + (size_t)(colBase + ni*16 + lane15)*NS + k0 + quad*8);
    #pragma unroll
    for (int mi = 0; mi < 4; ++mi)
      #pragma unroll
      for (int ni = 0; ni < 4; ++ni)
        acc[mi][ni] = __builtin_amdgcn_mfma_f32_16x16x32_bf16(a[mi], b[ni], acc[mi][ni], 0, 0, 0);
  }

  float sign = (by & 2) ? -1.f : 1.f;
  #pragma unroll
  for (int ni = 0; ni < 4; ++ni){
    float cs = 0.f;
    #pragma unroll
    for (int mi = 0; mi < 4; ++mi)
      #pragma unroll
      for (int r = 0; r < 4; ++r)
        cs += acc[mi][ni][r] * acc[mi][ni][r];
    cs += __shfl_xor(cs, 16);
    cs += __shfl_xor(cs, 32);
    if (quad == 0)
      atomicAdd(out + colBase + ni*16 + lane15, sign * cs);
  }
}

extern "C" void kernel_launch(void* const* d_in, const int* in_sizes, int n_in,
                              void* d_out, int out_size, void* d_ws, size_t ws_size,
                              hipStream_t stream) {
  const float* adds    = (const float*)d_in[0];
  const float* params  = (const float*)d_in[1];
  const float* weights = (const float*)d_in[2];
  const float* params2 = (const float*)d_in[3];
  float* out = (float*)d_out;
  int B = in_sizes[0] / NQ;   // 8192

  unsigned short* A2 = (unsigned short*)d_ws;        // 1024*512 bf16 = 1 MB
  unsigned short* cT = A2 + (size_t)M2 * NS;         // B*512 bf16 = 8 MB

  int prepBlocks = (B * 64 + 511) / 512;             // 1024
  hipLaunchKernelGGL(sim_prep, dim3(NS + prepBlocks), dim3(512), 0, stream,
                     params, weights, params2, adds, A2, cT, out, B);
  hipLaunchKernelGGL(gemm_out, dim3(B / 128, 8), dim3(256), 0, stream, A2, cT, out);
}